// Round 11
// baseline (369.441 us; speedup 1.0000x reference)
//
#include <hip/hip_runtime.h>
#include <math.h>

#define NQ 12
#define DIM 4096
#define NGATES 36
#define NROUND 9

typedef float f32x4 __attribute__((ext_vector_type(4)));
typedef __fp16 fp16x2 __attribute__((ext_vector_type(2)));
typedef __fp16 fp16x4 __attribute__((ext_vector_type(4)));
typedef __fp16 fp16x8 __attribute__((ext_vector_type(8)));

// GF(2)-linear LDS swizzle (bijective on 12 bits): sw(a^b) = sw(a)^sw(b)
constexpr unsigned swz(unsigned x) { return x ^ (x >> 4); }
constexpr int pc(unsigned x) { int c = 0; while (x) { c += (int)(x & 1u); x >>= 1; } return c; }
constexpr int topbit(unsigned x) { int b = -1; while (x) { ++b; x >>= 1; } return b; }

// row-echelon basis over GF(2), 12-bit vectors
struct Ech {
  unsigned piv[12] = {};
  constexpr unsigned reduce(unsigned x) const {
    while (x) { int b = topbit(x); if (!piv[b]) break; x ^= piv[b]; }
    return x;
  }
  constexpr bool add(unsigned x) {
    x = reduce(x); if (!x) return false; piv[topbit(x)] = x; return true;
  }
  constexpr bool contains(unsigned x) const { return reduce(x) == 0u; }
  constexpr int dim() const { int d = 0; for (int i = 0; i < 12; ++i) if (piv[i]) ++d; return d; }
};

// rank of the low-4-bit projections of n vectors over GF(2) == 4?
constexpr bool rank4(const unsigned* v, int n) {
  unsigned pivs[4] = {0, 0, 0, 0};
  int rk = 0;
  for (int i = 0; i < n; ++i) {
    unsigned x = v[i] & 15u;
    for (int bit = 3; bit >= 0; --bit) {
      if (!((x >> bit) & 1u)) continue;
      if (pivs[bit]) x ^= pivs[bit];
      else { pivs[bit] = x; ++rk; break; }
    }
  }
  return rk == 4;
}

// ---- compile-time circuit plan: CNOTs folded into GF(2) index maps ----
// 4 gates/round; round = dense 16x16 complex matrix on the slot subspace,
// applied to 256 cosets via MFMA. NEW: rounds are PAIRED (0,1)(2,3)(4,5)
// (6,7)+8 with SHARED wave directions, so within a pair each wave's
// round-(r+1) read-set equals its own round-r write-set -> the intra-pair
// __syncthreads() is dropped (verified by static_assert on span conditions).
struct Round {
  unsigned s[4];       // selectors of the 4 gates
  unsigned colD[4];    // 12-bit col direction vectors (lane bits 0..3)
  unsigned tD[2];      // tile direction vectors
  unsigned waveD[2];   // wave direction vectors (lane bits 6..7; shared in pair)
  unsigned cbsw8[16];  // swizzled byte offsets of the 16 coset slots
  unsigned dt[4];      // base8 XOR-delta for the 4 tiles
};
struct PlanT {
  Round rd[NROUND];
  unsigned zsel[NQ];
  bool ok;
};

constexpr PlanT make_plan() {
  PlanT P{};
  unsigned Mcol[NQ] = {}, Minv[NQ] = {};
  for (int i = 0; i < NQ; ++i) { Mcol[i] = 1u << i; Minv[i] = 1u << i; }
  unsigned gm[NGATES] = {}, gs[NGATES] = {};
  int g = 0;
  for (int L = 0; L < 3; ++L) {
    for (int q = 0; q < NQ; ++q) { int b = NQ - 1 - q; gm[g] = Mcol[b]; gs[g] = Minv[b]; ++g; }
    for (int q = 0; q < NQ; ++q) {
      int bc = NQ - 1 - q, bt = NQ - 1 - ((q + 1) % NQ);
      Mcol[bc] ^= Mcol[bt];
      Minv[bt] ^= Minv[bc];
    }
  }

  for (int pr = 0; pr < 5; ++pr) {
    const int r0 = 2 * pr;
    const int nr = (pr == 4) ? 1 : 2;
    // U10: combined mask span of the pair, padded to 10 dims with unit vecs
    Ech U{};
    for (int rr = 0; rr < nr; ++rr)
      for (int k = 0; k < 4; ++k) U.add(gm[4 * (r0 + rr) + k]);
    unsigned pad[12] = {}; int npad = 0;
    for (int i = 0; i < 12 && U.dim() < 10; ++i)
      if (U.add(1u << i)) pad[npad++] = 1u << i;
    // W: complete U10 to 12 dims -> shared wave directions
    Ech F = U;
    unsigned Wv[2] = {}; int nw = 0;
    for (int i = 0; i < 12 && nw < 2; ++i)
      if (F.add(1u << i)) Wv[nw++] = 1u << i;

    for (int rr = 0; rr < nr; ++rr) {
      const int r = r0 + rr;
      unsigned m[4], sl[4];
      for (int k = 0; k < 4; ++k) {
        m[k] = gm[4 * r + k]; sl[k] = gs[4 * r + k];
        P.rd[r].s[k] = sl[k];
      }
      unsigned cbu[16] = {};
      for (int d = 0; d < 16; ++d) {
        unsigned c = 0;
        for (int k = 0; k < 4; ++k) if ((d >> k) & 1) c ^= m[k];
        cbu[d] = swz(c);
        P.rd[r].cbsw8[d] = cbu[d] << 3;
      }
      // 6 completion dims within U10 (other round's masks first, then pads)
      Ech C{};
      for (int k = 0; k < 4; ++k) C.add(m[k]);
      unsigned comp[8] = {}; int nc = 0;
      for (int rr2 = 0; rr2 < nr; ++rr2) {
        if (rr2 == rr) continue;
        for (int k = 0; k < 4; ++k) {
          unsigned cand = gm[4 * (r0 + rr2) + k];
          if (nc < 6 && C.add(cand)) comp[nc++] = cand;
        }
      }
      for (int i = 0; i < npad && nc < 6; ++i)
        if (C.add(pad[i])) comp[nc++] = pad[i];
      // address images of the candidates (for bank-rank preference)
      unsigned av[6] = {};
      for (int i = 0; i < 6; ++i) {
        unsigned a = swz(comp[i]);
        for (int k = 0; k < 4; ++k) if (pc(comp[i] & sl[k]) & 1) a ^= cbu[1u << k];
        av[i] = a;
      }
      int bestmask = -1;
      for (int sm = 0; sm < 64 && bestmask < 0; ++sm) {
        if (pc((unsigned)sm) != 4) continue;
        unsigned v[6]; int vi = 0;
        for (int i = 0; i < 6; ++i) if ((sm >> i) & 1) v[vi++] = av[i];
        v[4] = cbu[4]; v[5] = cbu[8];
        if (rank4(v, 6)) bestmask = sm;
      }
      if (bestmask < 0) bestmask = 0x0F;
      int ci = 0, ti = 0;
      for (int i = 0; i < 6; ++i) {
        if ((bestmask >> i) & 1) { if (ci < 4) P.rd[r].colD[ci++] = comp[i]; }
        else { if (ti < 2) P.rd[r].tD[ti++] = comp[i]; }
      }
      P.rd[r].waveD[0] = Wv[0]; P.rd[r].waveD[1] = Wv[1];
      // tile deltas: addr-image of tile combos (incl. selector adjust)
      for (int tt = 0; tt < 4; ++tt) {
        unsigned jt = ((tt & 1) ? P.rd[r].tD[0] : 0u) ^ ((tt & 2) ? P.rd[r].tD[1] : 0u);
        unsigned d8 = swz(jt);
        for (int k = 0; k < 4; ++k) if (pc(jt & sl[k]) & 1) d8 ^= cbu[1u << k];
        P.rd[r].dt[tt] = d8 << 3;
      }
    }
  }
  for (int q = 0; q < NQ; ++q) P.zsel[q] = Minv[NQ - 1 - q];

  // ---- validity: bijectivity per round + pair span condition ----
  bool ok = true;
  for (int pr = 0; pr < 5; ++pr) {
    const int r0 = 2 * pr; const int nr = (pr == 4) ? 1 : 2;
    for (int rr = 0; rr < nr; ++rr) {
      const int r = r0 + rr;
      Ech B{};
      for (int k = 0; k < 4; ++k) ok = ok && B.add(gm[4 * r + k]);
      for (int k = 0; k < 4; ++k) ok = ok && B.add(P.rd[r].colD[k]);
      ok = ok && B.add(P.rd[r].tD[0]) && B.add(P.rd[r].tD[1]);
      ok = ok && B.add(P.rd[r].waveD[0]) && B.add(P.rd[r].waveD[1]);
      ok = ok && (B.dim() == 12);
    }
    if (nr == 2) {
      // wave-local set of round r0 must contain round r0+1's full read span
      Ech S{};
      for (int k = 0; k < 4; ++k) S.add(gm[4 * r0 + k]);
      for (int k = 0; k < 4; ++k) S.add(P.rd[r0].colD[k]);
      S.add(P.rd[r0].tD[0]); S.add(P.rd[r0].tD[1]);
      const int b = r0 + 1;
      for (int k = 0; k < 4; ++k) ok = ok && S.contains(gm[4 * b + k]);
      for (int k = 0; k < 4; ++k) ok = ok && S.contains(P.rd[b].colD[k]);
      ok = ok && S.contains(P.rd[b].tD[0]) && S.contains(P.rd[b].tD[1]);
    }
  }
  P.ok = ok;
  return P;
}

constexpr PlanT PLAN = make_plan();
static_assert(PLAN.ok, "plan span/bijectivity conditions violated");

// ---- prep: per round build the dense 16x16 complex tensor-product matrix,
// emit 4 fp16 A-operand matrices [16 rows s][32 k] row-major (hi/lo split).
__global__ void qc_prep(const float* __restrict__ params, __fp16* __restrict__ amat) {
  int t = threadIdx.x;             // 256 threads; 144 used
  int r = t >> 4, s = t & 15;
  if (r >= NROUND) return;
  float U[4][8];
  for (int k = 0; k < 4; ++k) {
    int gg = r * 4 + k;
    float h1 = params[3*gg+0]*0.5f, hh2 = params[3*gg+1]*0.5f, h3 = params[3*gg+2]*0.5f;
    float c1 = cosf(h1), s1 = sinf(h1);
    float c2 = cosf(hh2), s2 = sinf(hh2);
    float c3 = cosf(h3), s3 = sinf(h3);
    float a00r =  c2*c1, a00i =  s2*s1;
    float a01r = -s2*c1, a01i = -c2*s1;
    float a10r =  s2*c1, a10i = -c2*s1;
    float a11r =  c2*c1, a11i = -s2*s1;
    U[k][0] = c3*a00r + s3*a00i;  U[k][1] = c3*a00i - s3*a00r;
    U[k][2] = c3*a01r + s3*a01i;  U[k][3] = c3*a01i - s3*a01r;
    U[k][4] = c3*a10r - s3*a10i;  U[k][5] = c3*a10i + s3*a10r;
    U[k][6] = c3*a11r - s3*a11i;  U[k][7] = c3*a11i + s3*a11r;
  }
  __fp16* b0 = amat + r*2048 + s*32;   // Are_hi row
  __fp16* b1 = b0 + 512;               // Are_lo
  __fp16* b2 = b0 + 1024;              // Aim_hi
  __fp16* b3 = b0 + 1536;              // Aim_lo
  for (int j = 0; j < 16; ++j) {
    float pr = 1.f, pi = 0.f;
    for (int k = 0; k < 4; ++k) {
      int idx = ((((s >> k) & 1) * 2) + ((j >> k) & 1)) * 2;
      float gr = U[k][idx], gi = U[k][idx + 1];
      float npr = pr * gr - pi * gi;
      pi = pr * gi + pi * gr;
      pr = npr;
    }
    float v0_ =  pr; __fp16 e0 = (__fp16)v0_;
    float v1_ = -pi; __fp16 e1 = (__fp16)v1_;
    float v2_ =  pi; __fp16 e2 = (__fp16)v2_;
    float v3_ =  pr; __fp16 e3 = (__fp16)v3_;
    b0[2*j]   = e0;  b1[2*j]   = (__fp16)(v0_ - (float)e0);
    b0[2*j+1] = e1;  b1[2*j+1] = (__fp16)(v1_ - (float)e1);
    b2[2*j]   = e2;  b3[2*j]   = (__fp16)(v2_ - (float)e2);
    b2[2*j+1] = e3;  b3[2*j+1] = (__fp16)(v3_ - (float)e3);
  }
}

__global__ __launch_bounds__(256)
__attribute__((amdgpu_waves_per_eu(4, 5)))
void qc_main(const float* __restrict__ x, const __fp16* __restrict__ amat,
             float* __restrict__ out) {
  __shared__ float2 sst[DIM];        // 32768 B
  char* sb = (char*)sst;
  const int t = threadIdx.x;
  const long row = blockIdx.x;

  // ---- stage x row (im=0), accumulate sum of squares ----
  const float4* x4 = (const float4*)(x + (size_t)row * DIM);
  float ssq = 0.f;
#pragma unroll
  for (int k = 0; k < 4; ++k) {
    float4 a = x4[t + 256*k];
    int j0 = 4*(t + 256*k);
    *(float2*)(sb + (swz((unsigned)j0)     << 3)) = make_float2(a.x, 0.f);
    *(float2*)(sb + (swz((unsigned)(j0+1)) << 3)) = make_float2(a.y, 0.f);
    *(float2*)(sb + (swz((unsigned)(j0+2)) << 3)) = make_float2(a.z, 0.f);
    *(float2*)(sb + (swz((unsigned)(j0+3)) << 3)) = make_float2(a.w, 0.f);
    ssq += a.x*a.x + a.y*a.y + a.z*a.z + a.w*a.w;
  }
#pragma unroll
  for (int off = 32; off > 0; off >>= 1) ssq += __shfl_down(ssq, off, 64);
  __syncthreads();

  // ---- 9 rounds; dense 16x16 complex gate-product via MFMA.
  // Paired rounds share wave dirs: no barrier after rounds 0,2,4,6 (each
  // wave's next-round read-set is its own write-set; static_assert'd).
#pragma unroll 1
  for (int r = 0; r < NROUND; ++r) {
    const unsigned s0 = PLAN.rd[r].s[0], sA = PLAN.rd[r].s[1];
    const unsigned sB = PLAN.rd[r].s[2], sC = PLAN.rd[r].s[3];
    const unsigned cD0 = PLAN.rd[r].colD[0], cD1 = PLAN.rd[r].colD[1];
    const unsigned cD2 = PLAN.rd[r].colD[2], cD3 = PLAN.rd[r].colD[3];
    const unsigned W0 = PLAN.rd[r].waveD[0], W1 = PLAN.rd[r].waveD[1];
    const unsigned CB1 = PLAN.rd[r].cbsw8[1], CB2 = PLAN.rd[r].cbsw8[2];
    const unsigned CB3 = PLAN.rd[r].cbsw8[3];
    const unsigned C4 = PLAN.rd[r].cbsw8[4], C8 = PLAN.rd[r].cbsw8[8];
    const unsigned dts[4] = {0u, PLAN.rd[r].dt[1], PLAN.rd[r].dt[2], PLAN.rd[r].dt[3]};

    // coset rep for tile 0: XOR of chosen direction vectors
    unsigned j = 0;
    j ^= (unsigned)(-(int)((t >> 0) & 1)) & cD0;
    j ^= (unsigned)(-(int)((t >> 1) & 1)) & cD1;
    j ^= (unsigned)(-(int)((t >> 2) & 1)) & cD2;
    j ^= (unsigned)(-(int)((t >> 3) & 1)) & cD3;
    j ^= (unsigned)(-(int)((t >> 6) & 1)) & W0;
    j ^= (unsigned)(-(int)((t >> 7) & 1)) & W1;
    unsigned adj8 = 0;
    adj8 ^= (unsigned)(-(int)(__popc(j & s0) & 1)) & CB1;
    adj8 ^= (unsigned)(-(int)(__popc(j & sA) & 1)) & CB2;
    adj8 ^= (unsigned)(-(int)(__popc(j & sB) & 1)) & C4;
    adj8 ^= (unsigned)(-(int)(__popc(j & sC) & 1)) & C8;
    const unsigned q = ((unsigned)t >> 4) & 3u;
    const unsigned qsel = ((q & 1u) ? C4 : 0u) ^ ((q & 2u) ? C8 : 0u);
    const unsigned b0a = (((j ^ (j >> 4)) << 3) ^ adj8) ^ qsel;

    // A-operand fragments (uniform-ish global loads; L1/L2 resident)
    const fp16x8* am = (const fp16x8*)(amat + (size_t)r * 2048);
    const int fo = (t & 15) * 4 + (int)q;
    const fp16x8 Arh = am[fo];
    const fp16x8 Arl = am[64 + fo];
    const fp16x8 Aih = am[128 + fo];
    const fp16x8 Ail = am[192 + fo];

#pragma unroll
    for (int tt = 0; tt < 4; ++tt) {
      const unsigned bb = b0a ^ dts[tt];
      const unsigned a0 = bb, a1 = bb ^ CB1, a2 = bb ^ CB2, a3 = bb ^ CB3;
      const float2 A0 = *(const float2*)(sb + a0);
      const float2 A1 = *(const float2*)(sb + a1);
      const float2 A2 = *(const float2*)(sb + a2);
      const float2 A3 = *(const float2*)(sb + a3);
      // B fragment: k = q*8 + 2*jj + comp -> amp slot 4q+jj, re/im interleave
      fp16x2 p0 = __builtin_amdgcn_cvt_pkrtz(A0.x, A0.y);
      fp16x2 p1 = __builtin_amdgcn_cvt_pkrtz(A1.x, A1.y);
      fp16x2 p2 = __builtin_amdgcn_cvt_pkrtz(A2.x, A2.y);
      fp16x2 p3 = __builtin_amdgcn_cvt_pkrtz(A3.x, A3.y);
      fp16x2 q0 = __builtin_amdgcn_cvt_pkrtz(A0.x - (float)p0[0], A0.y - (float)p0[1]);
      fp16x2 q1 = __builtin_amdgcn_cvt_pkrtz(A1.x - (float)p1[0], A1.y - (float)p1[1]);
      fp16x2 q2 = __builtin_amdgcn_cvt_pkrtz(A2.x - (float)p2[0], A2.y - (float)p2[1]);
      fp16x2 q3 = __builtin_amdgcn_cvt_pkrtz(A3.x - (float)p3[0], A3.y - (float)p3[1]);
      fp16x4 u01 = __builtin_shufflevector(p0, p1, 0, 1, 2, 3);
      fp16x4 u23 = __builtin_shufflevector(p2, p3, 0, 1, 2, 3);
      fp16x8 Bhi = __builtin_shufflevector(u01, u23, 0, 1, 2, 3, 4, 5, 6, 7);
      fp16x4 w01 = __builtin_shufflevector(q0, q1, 0, 1, 2, 3);
      fp16x4 w23 = __builtin_shufflevector(q2, q3, 0, 1, 2, 3);
      fp16x8 Blo = __builtin_shufflevector(w01, w23, 0, 1, 2, 3, 4, 5, 6, 7);

      // 6-term hi/lo product (lo x lo dropped: ~2^-24 rel, negligible)
      f32x4 are = {0.f, 0.f, 0.f, 0.f}, aim = {0.f, 0.f, 0.f, 0.f};
      are = __builtin_amdgcn_mfma_f32_16x16x32_f16(Arh, Bhi, are, 0, 0, 0);
      are = __builtin_amdgcn_mfma_f32_16x16x32_f16(Arl, Bhi, are, 0, 0, 0);
      are = __builtin_amdgcn_mfma_f32_16x16x32_f16(Arh, Blo, are, 0, 0, 0);
      aim = __builtin_amdgcn_mfma_f32_16x16x32_f16(Aih, Bhi, aim, 0, 0, 0);
      aim = __builtin_amdgcn_mfma_f32_16x16x32_f16(Ail, Bhi, aim, 0, 0, 0);
      aim = __builtin_amdgcn_mfma_f32_16x16x32_f16(Aih, Blo, aim, 0, 0, 0);

      // C/D layout: col = lane&15 (coset), row = q*4+reg (slot) -> same addrs
      *(float2*)(sb + a0) = make_float2(are[0], aim[0]);
      *(float2*)(sb + a1) = make_float2(are[1], aim[1]);
      *(float2*)(sb + a2) = make_float2(are[2], aim[2]);
      *(float2*)(sb + a3) = make_float2(are[3], aim[3]);
    }
    // barrier only after odd rounds (pair boundaries) and the final round
    if ((r & 1) != 0 || r == NROUND - 1) __syncthreads();
  }

  // ---- measurement: 16 consecutive amps/thread, WHT over low 4 bits ----
  const unsigned mbase8 = (((16u * (unsigned)t) ^ (unsigned)t) << 3);
  float p[16];
#pragma unroll
  for (int c = 0; c < 16; ++c) {
    float2 v = *(const float2*)(sb + (mbase8 ^ ((unsigned)c << 3)));
    p[c] = v.x * v.x + v.y * v.y;
  }
#pragma unroll
  for (int b = 0; b < 4; ++b) {
#pragma unroll
    for (int c = 0; c < 16; ++c) {
      if (!(c & (1 << b))) {
        const int c1 = c | (1 << b);
        float u = p[c], v = p[c1];
        p[c] = u + v; p[c1] = u - v;
      }
    }
  }
  float zs[NQ];
#pragma unroll
  for (int qq = 0; qq < NQ; ++qq) {
    const unsigned m = PLAN.zsel[qq];
    const float v = p[m & 15u];
    const int sgn = __popc((unsigned)t & (m >> 4)) & 1;
    zs[qq] = sgn ? -v : v;
  }

  // ---- block reduction via LDS ----
  // layout: 6 float2 columns of 256 entries at k*2048; ssq at 12288;
  // partials at 12352.
  __syncthreads();               // all state reads done; safe to overwrite
#pragma unroll
  for (int k = 0; k < 6; ++k)
    *(float2*)(sb + (((unsigned)(k << 8) + (unsigned)t) << 3)) =
        make_float2(zs[2*k], zs[2*k+1]);
  if ((t & 63) == 0) *(float*)(sb + 12288 + (t >> 6) * 4) = ssq;
  __syncthreads();
  if (t < 192) {
    const int k = t >> 5, j = t & 31;
    const char* cbp = sb + (k << 11) + (j << 3);
    float2 acc = *(const float2*)(cbp);
#pragma unroll
    for (int i = 1; i < 8; ++i) {         // stride 32 entries: conflict-free
      float2 vv = *(const float2*)(cbp + i * 256);
      acc.x += vv.x; acc.y += vv.y;
    }
#pragma unroll
    for (int off = 16; off > 0; off >>= 1) {
      acc.x += __shfl_down(acc.x, off, 32);
      acc.y += __shfl_down(acc.y, off, 32);
    }
    if (j == 0) *(float2*)(sb + 12352 + (k << 3)) = acc;
  }
  __syncthreads();
  if (t < NQ) {
    const float* sq = (const float*)(sb + 12288);
    const float den = sq[0] + sq[1] + sq[2] + sq[3];
    out[row * NQ + t] = ((const float*)(sb + 12352))[t] / den;
  }
}

extern "C" void kernel_launch(void* const* d_in, const int* in_sizes, int n_in,
                              void* d_out, int out_size, void* d_ws, size_t ws_size,
                              hipStream_t stream) {
  const float* x = (const float*)d_in[0];
  const float* params = (const float*)d_in[1];
  float* out = (float*)d_out;
  __fp16* amat = (__fp16*)d_ws;                // 9 rounds * 4 mats * 16x32 fp16
  const int nrows = in_sizes[0] / DIM;         // 8192
  qc_prep<<<dim3(1), dim3(256), 0, stream>>>(params, amat);
  qc_main<<<dim3(nrows), dim3(256), 0, stream>>>(x, amat, out);
}

// Round 12
// 300.007 us; speedup vs baseline: 1.2314x; 1.2314x over previous
//
#include <hip/hip_runtime.h>
#include <math.h>

#define NQ 12
#define DIM 4096
#define NGATES 36
#define NROUND 9

typedef float f32x4 __attribute__((ext_vector_type(4)));
typedef __fp16 fp16x2 __attribute__((ext_vector_type(2)));
typedef __fp16 fp16x4 __attribute__((ext_vector_type(4)));
typedef __fp16 fp16x8 __attribute__((ext_vector_type(8)));

// residual via mixed-precision FMA: d = a - (f32)(p.lo / p.hi)  [1 op vs 3]
#define FMAMIX_LO(d, p, a) \
  asm("v_fma_mix_f32 %0, -%1, 1.0, %2 op_sel:[0,0,0] op_sel_hi:[1,0,0]" \
      : "=v"(d) : "v"(p), "v"(a))
#define FMAMIX_HI(d, p, a) \
  asm("v_fma_mix_f32 %0, -%1, 1.0, %2 op_sel:[1,0,0] op_sel_hi:[1,0,0]" \
      : "=v"(d) : "v"(p), "v"(a))

// GF(2)-linear LDS swizzle (bijective on 12 bits): sw(a^b) = sw(a)^sw(b)
constexpr unsigned swz(unsigned x) { return x ^ (x >> 4); }
constexpr int pc(unsigned x) { int c = 0; while (x) { c += (int)(x & 1u); x >>= 1; } return c; }

// rank of the low-4-bit projections of n vectors over GF(2)
constexpr bool rank4(const unsigned* v, int n) {
  unsigned pivs[4] = {0, 0, 0, 0};
  int rk = 0;
  for (int i = 0; i < n; ++i) {
    unsigned x = v[i] & 15u;
    for (int bit = 3; bit >= 0; --bit) {
      if (!((x >> bit) & 1u)) continue;
      if (pivs[bit]) x ^= pivs[bit];
      else { pivs[bit] = x; ++rk; break; }
    }
  }
  return rk == 4;
}

// ---- compile-time circuit plan: CNOTs folded into GF(2) index maps ----
// Gate on logical bit b: pair mask m = M*e_b, "1"-selector = row b of M^-1.
// 4 gates per round; round = dense 16x16 complex matrix on the 4-bit slot
// subspace, applied to 256 cosets via MFMA (K=32 re/im-interleaved).
struct Round {
  unsigned s[4];       // selectors of the 4 gates (plan slot-bit order)
  unsigned gidx[4];    // slot bit k <- original gate index (for prep)
  unsigned colD[4];    // 12-bit col direction vectors (lane bits 0..3)
  unsigned waveD[2];   // wave direction vectors (lane bits 6..7)
  unsigned cbsw8[16];  // swizzled byte offsets of the 16 coset slots
  unsigned dt[4];      // base8 XOR-delta for the 4 tiles
};
struct PlanT {
  Round rd[NROUND];
  unsigned zsel[NQ];
};

constexpr PlanT make_plan() {
  PlanT P{};
  unsigned Mcol[NQ] = {}, Minv[NQ] = {};
  for (int i = 0; i < NQ; ++i) { Mcol[i] = 1u << i; Minv[i] = 1u << i; }
  unsigned gm[NGATES] = {}, gs[NGATES] = {};
  int g = 0;
  for (int L = 0; L < 3; ++L) {
    for (int q = 0; q < NQ; ++q) { int b = NQ - 1 - q; gm[g] = Mcol[b]; gs[g] = Minv[b]; ++g; }
    for (int q = 0; q < NQ; ++q) {
      int bc = NQ - 1 - q, bt = NQ - 1 - ((q + 1) % NQ);
      Mcol[bc] ^= Mcol[bt];
      Minv[bt] ^= Minv[bc];
    }
  }
  for (int r = 0; r < NROUND; ++r) {
    unsigned m0[4], sl0[4];
    for (int k = 0; k < 4; ++k) { m0[k] = gm[4*r+k]; sl0[k] = gs[4*r+k]; }
    // pivots of the span of the 4 masks
    unsigned red[4];
    for (int k = 0; k < 4; ++k) red[k] = m0[k];
    for (int a = 0; a < 4; ++a) {
      unsigned pp = red[a] & (0u - red[a]);
      for (int b = a + 1; b < 4; ++b) if (red[b] & pp) red[b] ^= red[a];
    }
    unsigned piv[4];
    for (int a = 0; a < 4; ++a) piv[a] = red[a] & (0u - red[a]);
    for (int a = 0; a < 4; ++a)
      for (int b = a + 1; b < 4; ++b)
        if (piv[a] > piv[b]) { unsigned tp = piv[a]; piv[a] = piv[b]; piv[b] = tp; }
    unsigned l[4];
    for (int a = 0; a < 4; ++a) l[a] = piv[a] - 1u;
    // complement basis: D[i] = insert(1<<i) (zeros at pivot positions)
    unsigned D[8];
    for (int i = 0; i < 8; ++i) {
      unsigned j = 1u << i;
      j = ((j & ~l[0]) << 1) | (j & l[0]);
      j = ((j & ~l[1]) << 1) | (j & l[1]);
      j = ((j & ~l[2]) << 1) | (j & l[2]);
      j = ((j & ~l[3]) << 1) | (j & l[3]);
      D[i] = j;
    }
    // search: gate partition x col-dir 4-subset for rank-4 bank-pair map
    const int gp[3][4] = {{0,1,2,3},{0,2,1,3},{0,3,1,2}};
    int bp = -1; unsigned bS = 0;
    for (int p = 0; p < 3 && bp < 0; ++p) {
      unsigned mm[4], ss[4];
      for (int k = 0; k < 4; ++k) { mm[k] = m0[gp[p][k]]; ss[k] = sl0[gp[p][k]]; }
      unsigned cbu[16];
      for (int d = 0; d < 16; ++d) {
        unsigned c = 0;
        for (int k = 0; k < 4; ++k) if ((d >> k) & 1) c ^= mm[k];
        cbu[d] = swz(c);
      }
      for (unsigned S = 0; S < 256 && bp < 0; ++S) {
        if (pc(S) != 4) continue;
        unsigned v[6]; int vi = 0;
        for (int i = 0; i < 8; ++i) if ((S >> i) & 1) {
          unsigned av = swz(D[i]);
          for (int k = 0; k < 4; ++k) if (pc(D[i] & ss[k]) & 1) av ^= cbu[1u << k];
          v[vi++] = av;
        }
        v[4] = cbu[4]; v[5] = cbu[8];
        if (rank4(v, 6)) { bp = p; bS = S; }
      }
    }
    if (bp < 0) { bp = 0; bS = 0x0Fu; }   // fallback: original assignment
    // commit: selectors / gate order / cb table
    unsigned mm[4];
    for (int k = 0; k < 4; ++k) {
      P.rd[r].gidx[k] = (unsigned)gp[bp][k];
      P.rd[r].s[k]    = sl0[gp[bp][k]];
      mm[k]           = m0[gp[bp][k]];
    }
    unsigned cbu[16];
    for (int d = 0; d < 16; ++d) {
      unsigned c = 0;
      for (int k = 0; k < 4; ++k) if ((d >> k) & 1) c ^= mm[k];
      cbu[d] = swz(c);
      P.rd[r].cbsw8[d] = cbu[d] << 3;
    }
    // direction assignment: chosen 4 -> col; remaining: 2 -> tiles, 2 -> waves
    unsigned cD[4], TD[2], WD[2];
    int nc = 0, other[4]; int no = 0;
    for (int i = 0; i < 8; ++i) {
      if ((bS >> i) & 1) cD[nc++] = D[i];
      else other[no++] = i;
    }
    TD[0] = D[other[0]]; TD[1] = D[other[1]];
    WD[0] = D[other[2]]; WD[1] = D[other[3]];
    for (int k = 0; k < 4; ++k) P.rd[r].colD[k] = cD[k];
    P.rd[r].waveD[0] = WD[0]; P.rd[r].waveD[1] = WD[1];
    // tile deltas: full addr-image of the tile direction combos
    for (int tt = 0; tt < 4; ++tt) {
      unsigned jt = ((tt & 1) ? TD[0] : 0u) ^ ((tt & 2) ? TD[1] : 0u);
      unsigned d8 = swz(jt);
      for (int k = 0; k < 4; ++k) if (pc(jt & P.rd[r].s[k]) & 1) d8 ^= cbu[1u << k];
      P.rd[r].dt[tt] = d8 << 3;
    }
  }
  for (int q = 0; q < NQ; ++q) P.zsel[q] = Minv[NQ - 1 - q];
  return P;
}

constexpr PlanT PLAN = make_plan();

// ---- prep: per round build the dense 16x16 complex tensor-product matrix,
// emit 4 fp16 A-operand matrices [16 rows s][32 k] row-major (hi/lo split).
// Slot bit k corresponds to gate PLAN.rd[r].gidx[k] (plan gate order).
__global__ void qc_prep(const float* __restrict__ params, __fp16* __restrict__ amat) {
  int t = threadIdx.x;             // 256 threads; 144 used
  int r = t >> 4, s = t & 15;
  if (r >= NROUND) return;
  float U[4][8];
  for (int k = 0; k < 4; ++k) {
    int gg = r * 4 + (int)PLAN.rd[r].gidx[k];
    float h1 = params[3*gg+0]*0.5f, hh2 = params[3*gg+1]*0.5f, h3 = params[3*gg+2]*0.5f;
    float c1 = cosf(h1), s1 = sinf(h1);
    float c2 = cosf(hh2), s2 = sinf(hh2);
    float c3 = cosf(h3), s3 = sinf(h3);
    float a00r =  c2*c1, a00i =  s2*s1;
    float a01r = -s2*c1, a01i = -c2*s1;
    float a10r =  s2*c1, a10i = -c2*s1;
    float a11r =  c2*c1, a11i = -s2*s1;
    U[k][0] = c3*a00r + s3*a00i;  U[k][1] = c3*a00i - s3*a00r;
    U[k][2] = c3*a01r + s3*a01i;  U[k][3] = c3*a01i - s3*a01r;
    U[k][4] = c3*a10r - s3*a10i;  U[k][5] = c3*a10i + s3*a10r;
    U[k][6] = c3*a11r - s3*a11i;  U[k][7] = c3*a11i + s3*a11r;
  }
  __fp16* b0 = amat + r*2048 + s*32;   // Are_hi row
  __fp16* b1 = b0 + 512;               // Are_lo
  __fp16* b2 = b0 + 1024;              // Aim_hi
  __fp16* b3 = b0 + 1536;              // Aim_lo
  for (int j = 0; j < 16; ++j) {
    float pr = 1.f, pi = 0.f;
    for (int k = 0; k < 4; ++k) {
      int idx = ((((s >> k) & 1) * 2) + ((j >> k) & 1)) * 2;
      float gr = U[k][idx], gi = U[k][idx + 1];
      float npr = pr * gr - pi * gi;
      pi = pr * gi + pi * gr;
      pr = npr;
    }
    float v0_ =  pr; __fp16 e0 = (__fp16)v0_;
    float v1_ = -pi; __fp16 e1 = (__fp16)v1_;
    float v2_ =  pi; __fp16 e2 = (__fp16)v2_;
    float v3_ =  pr; __fp16 e3 = (__fp16)v3_;
    b0[2*j]   = e0;  b1[2*j]   = (__fp16)(v0_ - (float)e0);
    b0[2*j+1] = e1;  b1[2*j+1] = (__fp16)(v1_ - (float)e1);
    b2[2*j]   = e2;  b3[2*j]   = (__fp16)(v2_ - (float)e2);
    b2[2*j+1] = e3;  b3[2*j+1] = (__fp16)(v3_ - (float)e3);
  }
}

__global__ __launch_bounds__(256)
__attribute__((amdgpu_waves_per_eu(4, 5)))
void qc_main(const float* __restrict__ x, const __fp16* __restrict__ amat,
             float* __restrict__ out) {
  __shared__ float2 sst[DIM];        // 32768 B
  char* sb = (char*)sst;
  const int t = threadIdx.x;
  const long row = blockIdx.x;

  // ---- stage x row (im=0), accumulate sum of squares ----
  const float4* x4 = (const float4*)(x + (size_t)row * DIM);
  float ssq = 0.f;
#pragma unroll
  for (int k = 0; k < 4; ++k) {
    float4 a = x4[t + 256*k];
    int j0 = 4*(t + 256*k);
    *(float2*)(sb + (swz((unsigned)j0)     << 3)) = make_float2(a.x, 0.f);
    *(float2*)(sb + (swz((unsigned)(j0+1)) << 3)) = make_float2(a.y, 0.f);
    *(float2*)(sb + (swz((unsigned)(j0+2)) << 3)) = make_float2(a.z, 0.f);
    *(float2*)(sb + (swz((unsigned)(j0+3)) << 3)) = make_float2(a.w, 0.f);
    ssq += a.x*a.x + a.y*a.y + a.z*a.z + a.w*a.w;
  }
#pragma unroll
  for (int off = 32; off > 0; off >>= 1) ssq += __shfl_down(ssq, off, 64);
  __syncthreads();

  // ---- 9 rounds; dense 16x16 complex gate-product via MFMA (R7 structure,
  // monolithic per-tile; barrier every round). Residual split via fma_mix.
#pragma unroll 1
  for (int r = 0; r < NROUND; ++r) {
    const unsigned s0 = PLAN.rd[r].s[0], sA = PLAN.rd[r].s[1];
    const unsigned sB = PLAN.rd[r].s[2], sC = PLAN.rd[r].s[3];
    const unsigned cD0 = PLAN.rd[r].colD[0], cD1 = PLAN.rd[r].colD[1];
    const unsigned cD2 = PLAN.rd[r].colD[2], cD3 = PLAN.rd[r].colD[3];
    const unsigned W0 = PLAN.rd[r].waveD[0], W1 = PLAN.rd[r].waveD[1];
    const unsigned CB1 = PLAN.rd[r].cbsw8[1], CB2 = PLAN.rd[r].cbsw8[2];
    const unsigned CB3 = PLAN.rd[r].cbsw8[3];
    const unsigned C4 = PLAN.rd[r].cbsw8[4], C8 = PLAN.rd[r].cbsw8[8];
    const unsigned dts[4] = {0u, PLAN.rd[r].dt[1], PLAN.rd[r].dt[2], PLAN.rd[r].dt[3]};

    // coset rep for tile 0: XOR of chosen direction vectors
    unsigned j = 0;
    j ^= (unsigned)(-(int)((t >> 0) & 1)) & cD0;
    j ^= (unsigned)(-(int)((t >> 1) & 1)) & cD1;
    j ^= (unsigned)(-(int)((t >> 2) & 1)) & cD2;
    j ^= (unsigned)(-(int)((t >> 3) & 1)) & cD3;
    j ^= (unsigned)(-(int)((t >> 6) & 1)) & W0;
    j ^= (unsigned)(-(int)((t >> 7) & 1)) & W1;
    unsigned adj8 = 0;
    adj8 ^= (unsigned)(-(int)(__popc(j & s0) & 1)) & CB1;
    adj8 ^= (unsigned)(-(int)(__popc(j & sA) & 1)) & CB2;
    adj8 ^= (unsigned)(-(int)(__popc(j & sB) & 1)) & C4;
    adj8 ^= (unsigned)(-(int)(__popc(j & sC) & 1)) & C8;
    const unsigned q = ((unsigned)t >> 4) & 3u;
    const unsigned qsel = ((q & 1u) ? C4 : 0u) ^ ((q & 2u) ? C8 : 0u);
    const unsigned b0a = (((j ^ (j >> 4)) << 3) ^ adj8) ^ qsel;

    // A-operand fragments (uniform-ish global loads; L1/L2 resident)
    const fp16x8* am = (const fp16x8*)(amat + (size_t)r * 2048);
    const int fo = (t & 15) * 4 + (int)q;
    const fp16x8 Arh = am[fo];
    const fp16x8 Arl = am[64 + fo];
    const fp16x8 Aih = am[128 + fo];
    const fp16x8 Ail = am[192 + fo];

#pragma unroll
    for (int tt = 0; tt < 4; ++tt) {
      const unsigned bb = b0a ^ dts[tt];
      const unsigned a0 = bb, a1 = bb ^ CB1, a2 = bb ^ CB2, a3 = bb ^ CB3;
      const float2 A0 = *(const float2*)(sb + a0);
      const float2 A1 = *(const float2*)(sb + a1);
      const float2 A2 = *(const float2*)(sb + a2);
      const float2 A3 = *(const float2*)(sb + a3);
      // B fragment: k = q*8 + 2*jj + comp -> amp slot 4q+jj, re/im interleave
      fp16x2 p0 = __builtin_amdgcn_cvt_pkrtz(A0.x, A0.y);
      fp16x2 p1 = __builtin_amdgcn_cvt_pkrtz(A1.x, A1.y);
      fp16x2 p2 = __builtin_amdgcn_cvt_pkrtz(A2.x, A2.y);
      fp16x2 p3 = __builtin_amdgcn_cvt_pkrtz(A3.x, A3.y);
      // residuals in ONE mixed-precision FMA each (was cvt+cvt+sub+sub)
      float r0x, r0y, r1x, r1y, r2x, r2y, r3x, r3y;
      FMAMIX_LO(r0x, p0, A0.x); FMAMIX_HI(r0y, p0, A0.y);
      FMAMIX_LO(r1x, p1, A1.x); FMAMIX_HI(r1y, p1, A1.y);
      FMAMIX_LO(r2x, p2, A2.x); FMAMIX_HI(r2y, p2, A2.y);
      FMAMIX_LO(r3x, p3, A3.x); FMAMIX_HI(r3y, p3, A3.y);
      fp16x2 q0 = __builtin_amdgcn_cvt_pkrtz(r0x, r0y);
      fp16x2 q1 = __builtin_amdgcn_cvt_pkrtz(r1x, r1y);
      fp16x2 q2 = __builtin_amdgcn_cvt_pkrtz(r2x, r2y);
      fp16x2 q3 = __builtin_amdgcn_cvt_pkrtz(r3x, r3y);
      fp16x4 u01 = __builtin_shufflevector(p0, p1, 0, 1, 2, 3);
      fp16x4 u23 = __builtin_shufflevector(p2, p3, 0, 1, 2, 3);
      fp16x8 Bhi = __builtin_shufflevector(u01, u23, 0, 1, 2, 3, 4, 5, 6, 7);
      fp16x4 w01 = __builtin_shufflevector(q0, q1, 0, 1, 2, 3);
      fp16x4 w23 = __builtin_shufflevector(q2, q3, 0, 1, 2, 3);
      fp16x8 Blo = __builtin_shufflevector(w01, w23, 0, 1, 2, 3, 4, 5, 6, 7);

      // 6-term hi/lo product (lo x lo dropped: ~2^-24 rel, negligible)
      f32x4 are = {0.f, 0.f, 0.f, 0.f}, aim = {0.f, 0.f, 0.f, 0.f};
      are = __builtin_amdgcn_mfma_f32_16x16x32_f16(Arh, Bhi, are, 0, 0, 0);
      are = __builtin_amdgcn_mfma_f32_16x16x32_f16(Arl, Bhi, are, 0, 0, 0);
      are = __builtin_amdgcn_mfma_f32_16x16x32_f16(Arh, Blo, are, 0, 0, 0);
      aim = __builtin_amdgcn_mfma_f32_16x16x32_f16(Aih, Bhi, aim, 0, 0, 0);
      aim = __builtin_amdgcn_mfma_f32_16x16x32_f16(Ail, Bhi, aim, 0, 0, 0);
      aim = __builtin_amdgcn_mfma_f32_16x16x32_f16(Aih, Blo, aim, 0, 0, 0);

      // C/D layout: col = lane&15 (coset), row = q*4+reg (slot) -> same addrs
      *(float2*)(sb + a0) = make_float2(are[0], aim[0]);
      *(float2*)(sb + a1) = make_float2(are[1], aim[1]);
      *(float2*)(sb + a2) = make_float2(are[2], aim[2]);
      *(float2*)(sb + a3) = make_float2(are[3], aim[3]);
    }
    __syncthreads();
  }

  // ---- measurement: 16 consecutive amps/thread, WHT over low 4 bits ----
  const unsigned mbase8 = (((16u * (unsigned)t) ^ (unsigned)t) << 3);
  float p[16];
#pragma unroll
  for (int c = 0; c < 16; ++c) {
    float2 v = *(const float2*)(sb + (mbase8 ^ ((unsigned)c << 3)));
    p[c] = v.x * v.x + v.y * v.y;
  }
#pragma unroll
  for (int b = 0; b < 4; ++b) {
#pragma unroll
    for (int c = 0; c < 16; ++c) {
      if (!(c & (1 << b))) {
        const int c1 = c | (1 << b);
        float u = p[c], v = p[c1];
        p[c] = u + v; p[c1] = u - v;
      }
    }
  }
  float zs[NQ];
#pragma unroll
  for (int qq = 0; qq < NQ; ++qq) {
    const unsigned m = PLAN.zsel[qq];
    const float v = p[m & 15u];
    const int sgn = __popc((unsigned)t & (m >> 4)) & 1;
    zs[qq] = sgn ? -v : v;
  }

  // ---- block reduction via LDS ----
  // layout: 6 float2 columns of 256 entries at k*2048; ssq at 12288;
  // partials at 12352.
  __syncthreads();               // all state reads done; safe to overwrite
#pragma unroll
  for (int k = 0; k < 6; ++k)
    *(float2*)(sb + (((unsigned)(k << 8) + (unsigned)t) << 3)) =
        make_float2(zs[2*k], zs[2*k+1]);
  if ((t & 63) == 0) *(float*)(sb + 12288 + (t >> 6) * 4) = ssq;
  __syncthreads();
  if (t < 192) {
    const int k = t >> 5, j = t & 31;
    const char* cbp = sb + (k << 11) + (j << 3);
    float2 acc = *(const float2*)(cbp);
#pragma unroll
    for (int i = 1; i < 8; ++i) {         // stride 32 entries: conflict-free
      float2 vv = *(const float2*)(cbp + i * 256);
      acc.x += vv.x; acc.y += vv.y;
    }
#pragma unroll
    for (int off = 16; off > 0; off >>= 1) {
      acc.x += __shfl_down(acc.x, off, 32);
      acc.y += __shfl_down(acc.y, off, 32);
    }
    if (j == 0) *(float2*)(sb + 12352 + (k << 3)) = acc;
  }
  __syncthreads();
  if (t < NQ) {
    const float* sq = (const float*)(sb + 12288);
    const float den = sq[0] + sq[1] + sq[2] + sq[3];
    out[row * NQ + t] = ((const float*)(sb + 12352))[t] / den;
  }
}

extern "C" void kernel_launch(void* const* d_in, const int* in_sizes, int n_in,
                              void* d_out, int out_size, void* d_ws, size_t ws_size,
                              hipStream_t stream) {
  const float* x = (const float*)d_in[0];
  const float* params = (const float*)d_in[1];
  float* out = (float*)d_out;
  __fp16* amat = (__fp16*)d_ws;                // 9 rounds * 4 mats * 16x32 fp16
  const int nrows = in_sizes[0] / DIM;         // 8192
  qc_prep<<<dim3(1), dim3(256), 0, stream>>>(params, amat);
  qc_main<<<dim3(nrows), dim3(256), 0, stream>>>(x, amat, out);
}